// Round 7
// baseline (250.989 us; speedup 1.0000x reference)
//
#include <hip/hip_runtime.h>
#include <cstdint>
#include <cstddef>

#define N_COLS 4096
#define TPB 256
#define WPB 4                      // waves per block = rows per block (fully independent)
#define CSTR 260                   // words per histogram copy (bank-rotating stride)
#define SURV_CAP 64

// --- kernel 1: boost factors, double-precision exp rounded to fp32 ---
__global__ void boost_kernel(const float* __restrict__ dc,
                             const int* __restrict__ kp,
                             float* __restrict__ bf) {
    int i = blockIdx.x * blockDim.x + threadIdx.x;
    if (i < N_COLS) {
        float td = (float)kp[0] / (float)N_COLS;   // float32(k)/float32(n), like ref
        float arg = td - dc[i];                    // fp32 subtract, like ref
        bf[i] = (float)exp((double)arg);           // ~correctly-rounded fp32 exp
    }
}

__device__ __forceinline__ uint32_t orderable(uint32_t u) {
    return (u & 0x80000000u) ? ~u : (u | 0x80000000u);  // float order == uint order
}

// Wave-local LDS fence: each wave owns its histogram/survivor region, so
// ordering needs only lgkmcnt(0) within the wave — NO s_barrier anywhere.
__device__ __forceinline__ void wave_lgkm() {
    asm volatile("s_waitcnt lgkmcnt(0)" ::: "memory");
}

// One wave per row, ZERO block barriers, stream-consume design:
// the row is NEVER retained — pass 1 histograms values as the loads
// arrive (the load phase IS the hist phase), later passes re-read the
// row from L1/L2 (R2 proved FETCH stays ~65 MB: re-reads are cache-hot).
// Register allocation left NATURAL (round-5's sole failure was
// __launch_bounds__(256,8) forcing VGPR=32 and spilling; round-2/5
// established the correctness of this zero-barrier scheme). ~60 VGPR +
// 9.7 KB LDS allow 8 blocks x 4 waves = 32 independent rows per CU;
// contention staggers them so scan/descent windows hide under other
// waves' streaming.
__global__ __launch_bounds__(TPB) void kwinner_kernel(
    const float* __restrict__ x, const float* __restrict__ bf,
    const int* __restrict__ kp, float* __restrict__ out, int rows)
{
    __shared__ __align__(16) uint32_t s_hist[WPB][2][CSTR];    // per-wave, 2 copies
    __shared__ uint32_t s_cand[WPB][SURV_CAP];                 // per-wave survivors
    __shared__ uint32_t s_m2[WPB * 8];                         // per-wave counter, bank-spread

    const int tid  = threadIdx.x;
    const int w    = tid >> 6;
    const int lane = tid & 63;

    size_t row = (size_t)blockIdx.x * WPB + (size_t)w;
    const size_t rmax = (size_t)rows - 1;     // ragged tail: clamp -> benign duplicate write
    if (row > rmax) row = rmax;

    const float4* xr   = (const float4*)(x + row * (size_t)N_COLS);
    float4*       orow = (float4*)(out + row * (size_t)N_COLS);
    const float4* bfr  = (const float4*)bf;   // 16 KB shared by all blocks: L2-resident

    uint32_t* hist = &s_hist[w][0][0];
    uint32_t* m2p  = &s_m2[w * 8];

    // clear my histogram (each lane: 4 bins per copy) + survivor counter
    {
        uint4 z; z.x = z.y = z.z = z.w = 0u;
        *(uint4*)&hist[4 * lane]        = z;
        *(uint4*)&hist[CSTR + 4 * lane] = z;
        if (lane == 0) *m2p = 0u;
    }
    wave_lgkm();

    // pass 1 (hist): stream the row, consume values AS THEY ARRIVE — the
    // wave is memory-active for nearly this whole phase. Composite digit
    // d = min((bits>>16) - 0x3F80, 255): monotone for all floats >= 1.0.
    const uint32_t cofs = (uint32_t)(lane & 1) * CSTR;   // 2 copies within the wave
    const float T0f = 1.10f;   // performance heuristic only; exactness guarded below
    #pragma unroll
    for (int jj = 0; jj < 16; ++jj) {
        float4 v = xr[lane + 64 * jj];
        float4 b = bfr[lane + 64 * jj];
        float p0 = v.x * b.x, p1 = v.y * b.y, p2 = v.z * b.z, p3 = v.w * b.w;
        if (p0 >= T0f) { uint32_t d = (__float_as_uint(p0) >> 16) - 0x3F80u; d = d > 255u ? 255u : d; atomicAdd(&hist[cofs + d], 1u); }
        if (p1 >= T0f) { uint32_t d = (__float_as_uint(p1) >> 16) - 0x3F80u; d = d > 255u ? 255u : d; atomicAdd(&hist[cofs + d], 1u); }
        if (p2 >= T0f) { uint32_t d = (__float_as_uint(p2) >> 16) - 0x3F80u; d = d > 255u ? 255u : d; atomicAdd(&hist[cofs + d], 1u); }
        if (p3 >= T0f) { uint32_t d = (__float_as_uint(p3) >> 16) - 0x3F80u; d = d > 255u ? 255u : d; atomicAdd(&hist[cofs + d], 1u); }
    }
    wave_lgkm();

    const uint32_t k = (uint32_t)kp[0];
    uint32_t rem = k;

    // per-wave copy-reduce + suffix-scan + digit pick (conflict-light uint4 reads)
    uint32_t dsel, packed;
    {
        uint4 a  = *(const uint4*)&hist[4 * lane];
        uint4 b2 = *(const uint4*)&hist[CSTR + 4 * lane];
        uint32_t vv0 = a.x + b2.x, vv1 = a.y + b2.y, vv2 = a.z + b2.z, vv3 = a.w + b2.w;
        uint32_t s3 = vv3, s2 = vv2 + s3, s1 = vv1 + s2, s0 = vv0 + s1;
        uint32_t T = s0;
        #pragma unroll
        for (int off = 1; off < 64; off <<= 1) {
            uint32_t t = (uint32_t)__shfl_down((int)T, off, 64);
            if (lane + off < 64) T += t;
        }
        uint32_t Tex = T - s0;   // sum over lanes > lane
        uint32_t S0 = Tex + s0, S1 = Tex + s1, S2 = Tex + s2, S3 = Tex + s3;
        int b = -1; uint32_t sn = 0;
        if (S3 >= rem)      { b = 3; sn = S3 - vv3; }
        else if (S2 >= rem) { b = 2; sn = S2 - vv2; }
        else if (S1 >= rem) { b = 1; sn = S1 - vv1; }
        else if (S0 >= rem) { b = 0; sn = S0 - vv0; }
        packed = (b >= 0) ? ((((uint32_t)(4 * lane + b + 1)) << 16) | sn) : 0u;
        #pragma unroll
        for (int off = 1; off < 64; off <<= 1) {
            uint32_t o = (uint32_t)__shfl_xor((int)packed, off, 64);
            packed = packed > o ? packed : o;
        }
        dsel = (packed >> 16) - 1u;      // selected digit (if packed != 0)
        rem -= (packed & 0xFFFFu);       // rank within selected bin
    }

    float thr = 0.0f;
    bool need_fallback = (packed == 0u) || (dsel == 255u);

    if (!need_fallback) {
        const uint32_t hi16 = 0x3F80u + dsel;
        // pass 2 (survivors): re-read row (cache-hot), recompute products
        // bit-identically, scatter bin members. May include a few elements
        // in [1.09375, T0) when dsel==0x0C — all strictly below every
        // histogrammed member, and rem <= member count, so the rem-th
        // largest is unaffected.
        #pragma unroll
        for (int jj = 0; jj < 16; ++jj) {
            float4 v = xr[lane + 64 * jj];
            float4 b = bfr[lane + 64 * jj];
            uint32_t u0 = __float_as_uint(v.x * b.x), u1 = __float_as_uint(v.y * b.y);
            uint32_t u2 = __float_as_uint(v.z * b.z), u3 = __float_as_uint(v.w * b.w);
            if ((u0 >> 16) == hi16) { uint32_t p = atomicAdd(m2p, 1u); if (p < SURV_CAP) s_cand[w][p] = u0; }
            if ((u1 >> 16) == hi16) { uint32_t p = atomicAdd(m2p, 1u); if (p < SURV_CAP) s_cand[w][p] = u1; }
            if ((u2 >> 16) == hi16) { uint32_t p = atomicAdd(m2p, 1u); if (p < SURV_CAP) s_cand[w][p] = u2; }
            if ((u3 >> 16) == hi16) { uint32_t p = atomicAdd(m2p, 1u); if (p < SURV_CAP) s_cand[w][p] = u3; }
        }
        wave_lgkm();
        const uint32_t m2 = *m2p;
        if (m2 <= SURV_CAP) {
            // per-wave 16-bit ballot descent over this wave's survivors
            uint32_t cv = ((uint32_t)lane < m2) ? s_cand[w][lane] : ((~hi16) << 16);
            uint32_t cur = 0;
            #pragma unroll
            for (int bpos = 15; bpos >= 0; --bpos) {
                uint32_t t  = (hi16 << 16) | cur | (1u << bpos);
                uint32_t mk = ~((1u << bpos) - 1u);
                uint32_t c  = (uint32_t)__popcll(__ballot(((cv ^ t) & mk) == 0u));
                if (c >= rem) cur |= (1u << bpos);
                else          rem -= c;
            }
            thr = __uint_as_float((hi16 << 16) | cur);
        } else {
            need_fallback = true;
        }
    }

    if (need_fallback) {
        // exact 4-pass orderable radix over all 4096 elements (any input),
        // wave-synchronous on this wave's private histogram; row re-read
        // each pass (rare path, cache-hot).
        {
            uint4 z; z.x = z.y = z.z = z.w = 0u;
            *(uint4*)&hist[4 * lane]        = z;
            *(uint4*)&hist[CSTR + 4 * lane] = z;
        }
        wave_lgkm();
        uint32_t prefix = 0;
        rem = k;
        const uint32_t pmasks[4] = {0u, 0xFF000000u, 0xFFFF0000u, 0xFFFFFF00u};
        #pragma unroll 1
        for (int pass = 0; pass < 4; ++pass) {
            const int shift = 24 - pass * 8;
            const uint32_t pm = pmasks[pass];
            #pragma unroll
            for (int jj = 0; jj < 16; ++jj) {
                float4 v = xr[lane + 64 * jj];
                float4 b = bfr[lane + 64 * jj];
                uint32_t ou;
                ou = orderable(__float_as_uint(v.x * b.x));
                if (((ou ^ prefix) & pm) == 0u) atomicAdd(&hist[cofs + ((ou >> shift) & 255u)], 1u);
                ou = orderable(__float_as_uint(v.y * b.y));
                if (((ou ^ prefix) & pm) == 0u) atomicAdd(&hist[cofs + ((ou >> shift) & 255u)], 1u);
                ou = orderable(__float_as_uint(v.z * b.z));
                if (((ou ^ prefix) & pm) == 0u) atomicAdd(&hist[cofs + ((ou >> shift) & 255u)], 1u);
                ou = orderable(__float_as_uint(v.w * b.w));
                if (((ou ^ prefix) & pm) == 0u) atomicAdd(&hist[cofs + ((ou >> shift) & 255u)], 1u);
            }
            wave_lgkm();
            uint4 a  = *(const uint4*)&hist[4 * lane];
            uint4 b2 = *(const uint4*)&hist[CSTR + 4 * lane];
            {
                uint4 z; z.x = z.y = z.z = z.w = 0u;
                *(uint4*)&hist[4 * lane]        = z;
                *(uint4*)&hist[CSTR + 4 * lane] = z;
            }
            wave_lgkm();   // zeros land before next pass's atomics
            uint32_t vv0 = a.x + b2.x, vv1 = a.y + b2.y, vv2 = a.z + b2.z, vv3 = a.w + b2.w;
            uint32_t s3 = vv3, s2 = vv2 + s3, s1 = vv1 + s2, s0 = vv0 + s1;
            uint32_t T = s0;
            #pragma unroll
            for (int off = 1; off < 64; off <<= 1) {
                uint32_t t = (uint32_t)__shfl_down((int)T, off, 64);
                if (lane + off < 64) T += t;
            }
            uint32_t Tex = T - s0;
            uint32_t S0 = Tex + s0, S1 = Tex + s1, S2 = Tex + s2, S3 = Tex + s3;
            int b = -1; uint32_t sn = 0;
            if (S3 >= rem)      { b = 3; sn = S3 - vv3; }
            else if (S2 >= rem) { b = 2; sn = S2 - vv2; }
            else if (S1 >= rem) { b = 1; sn = S1 - vv1; }
            else if (S0 >= rem) { b = 0; sn = S0 - vv0; }
            uint32_t pk = (b >= 0) ? ((((uint32_t)(4 * lane + b + 1)) << 16) | sn) : 0u;
            #pragma unroll
            for (int off = 1; off < 64; off <<= 1) {
                uint32_t o = (uint32_t)__shfl_xor((int)pk, off, 64);
                pk = pk > o ? pk : o;
            }
            prefix |= ((pk >> 16) - 1u) << shift;
            rem -= (pk & 0xFFFFu);
        }
        // orderable-space -> float bits
        uint32_t tu = (prefix & 0x80000000u) ? (prefix & 0x7FFFFFFFu) : ~prefix;
        thr = __uint_as_float(tu);
    }

    // pass 3 (epilogue): re-read row (cache-hot), recompute bit-identical
    // products, mask against thr, store.
    #pragma unroll
    for (int jj = 0; jj < 16; ++jj) {
        float4 v = xr[lane + 64 * jj];
        float4 b = bfr[lane + 64 * jj];
        float4 o;
        o.x = (v.x * b.x >= thr) ? v.x : 0.0f;
        o.y = (v.y * b.y >= thr) ? v.y : 0.0f;
        o.z = (v.z * b.z >= thr) ? v.z : 0.0f;
        o.w = (v.w * b.w >= thr) ? v.w : 0.0f;
        orow[lane + 64 * jj] = o;
    }
}

extern "C" void kernel_launch(void* const* d_in, const int* in_sizes, int n_in,
                              void* d_out, int out_size, void* d_ws, size_t ws_size,
                              hipStream_t stream) {
    const float* x  = (const float*)d_in[0];
    const float* dc = (const float*)d_in[1];
    const int*   kp = (const int*)d_in[2];
    float* out = (float*)d_out;
    float* bf  = (float*)d_ws;                 // 4096 floats of scratch

    const int n    = in_sizes[1];              // 4096
    const int rows = in_sizes[0] / n;          // 8192

    boost_kernel<<<(n + TPB - 1) / TPB, TPB, 0, stream>>>(dc, kp, bf);
    const int nb = (rows + WPB - 1) / WPB;     // 2048 blocks, 4 independent wave-rows each
    kwinner_kernel<<<nb, TPB, 0, stream>>>(x, bf, kp, out, rows);
}

// Round 8
// 230.218 us; speedup vs baseline: 1.0902x; 1.0902x over previous
//
#include <hip/hip_runtime.h>
#include <cstdint>
#include <cstddef>

#define N_COLS 4096
#define TPB 256
#define NCOPY 8
#define CSTR 260                   // words per copy (copy-major, bank-rotating stride)
#define NHWORDS (NCOPY * CSTR)     // 2080 words = 8320 B
#define SURV_CAP 64

// --- kernel 1: boost factors, double-precision exp rounded to fp32 ---
__global__ void boost_kernel(const float* __restrict__ dc,
                             const int* __restrict__ kp,
                             float* __restrict__ bf) {
    int i = blockIdx.x * blockDim.x + threadIdx.x;
    if (i < N_COLS) {
        float td = (float)kp[0] / (float)N_COLS;   // float32(k)/float32(n), like ref
        float arg = td - dc[i];                    // fp32 subtract, like ref
        bf[i] = (float)exp((double)arg);           // ~correctly-rounded fp32 exp
    }
}

__device__ __forceinline__ uint32_t orderable(uint32_t u) {
    return (u & 0x80000000u) ? ~u : (u | 0x80000000u);  // float order == uint order
}

// one block per row; 16 boosted values per thread in registers (round-0
// structure — the proven-best point — with exactly two surgical fixes:
// copy-major conflict-free histogram, and ballot-based digit pick).
__global__ __launch_bounds__(TPB) void kwinner_kernel(
    const float* __restrict__ x, const float* __restrict__ bf,
    const int* __restrict__ kp, float* __restrict__ out)
{
    __shared__ __align__(16) uint32_t s_hist[NHWORDS];  // copy-major: [copy*CSTR + bin]
    __shared__ uint32_t s_cnt[256];        // fallback only
    __shared__ uint32_t s_cand[SURV_CAP];
    __shared__ uint32_t s_m2;

    const int tid  = threadIdx.x;
    const int lane = tid & 63;
    const uint32_t copy = (uint32_t)(tid & (NCOPY - 1));
    const size_t row = blockIdx.x;
    const float4* xr = (const float4*)(x + row * (size_t)N_COLS);
    const float4* br = (const float4*)bf;
    float4* orow = (float4*)(out + row * (size_t)N_COLS);

    float4 xv[4];
    float xb[16];
    #pragma unroll
    for (int j = 0; j < 4; ++j) {
        float4 v = xr[tid + j * TPB];
        float4 b = br[tid + j * TPB];
        xv[j] = v;
        xb[j * 4 + 0] = v.x * b.x;
        xb[j * 4 + 1] = v.y * b.y;
        xb[j * 4 + 2] = v.z * b.z;
        xb[j * 4 + 3] = v.w * b.w;
    }

    // clear histogram (vectorized) + survivor counter
    {
        uint4* h4 = (uint4*)s_hist;
        uint4 z; z.x = z.y = z.z = z.w = 0u;
        #pragma unroll
        for (int j = 0; j < 3; ++j) {
            int idx = tid + j * TPB;
            if (idx < NHWORDS / 4) h4[idx] = z;
        }
    }
    if (tid == 0) s_m2 = 0;
    __syncthreads();

    // single histogram pass over candidates >= T0 with the composite digit
    // d = min((bits>>16) - 0x3F80, 255): monotone for all floats >= 1.0.
    // copy-major: atomics from the 8 copies hit rotated banks (260%32=4).
    const float T0f = 1.10f;   // performance heuristic only; exactness guarded below
    uint32_t* hc = &s_hist[copy * CSTR];
    #pragma unroll
    for (int e = 0; e < 16; ++e) {
        if (xb[e] >= T0f) {
            uint32_t d = (__float_as_uint(xb[e]) >> 16) - 0x3F80u;
            d = d > 255u ? 255u : d;
            atomicAdd(&hc[d], 1u);
        }
    }
    __syncthreads();

    const uint32_t k = (uint32_t)kp[0];
    uint32_t rem = k;

    // fused copy-reduce + suffix-scan + ballot digit pick, replicated per wave.
    // copy-major reduce: per-copy uint4 reads are stride-16B -> conflict-free.
    uint32_t dsel;
    uint32_t sel;
    {
        uint32_t vv0 = 0, vv1 = 0, vv2 = 0, vv3 = 0;
        #pragma unroll
        for (int c = 0; c < NCOPY; ++c) {
            uint4 a = *(const uint4*)&s_hist[c * CSTR + 4 * lane];
            vv0 += a.x; vv1 += a.y; vv2 += a.z; vv3 += a.w;
        }
        uint32_t s3 = vv3, s2 = vv2 + s3, s1 = vv1 + s2, s0 = vv0 + s1;
        uint32_t T = s0;
        #pragma unroll
        for (int off = 1; off < 64; off <<= 1) {
            uint32_t t = (uint32_t)__shfl_down((int)T, off, 64);
            if (lane + off < 64) T += t;
        }
        uint32_t Tex = T - s0;   // sum over lanes > lane
        uint32_t S0 = Tex + s0, S1 = Tex + s1, S2 = Tex + s2, S3 = Tex + s3;
        int b = -1; uint32_t sn = 0;
        if (S3 >= rem)      { b = 3; sn = S3 - vv3; }
        else if (S2 >= rem) { b = 2; sn = S2 - vv2; }
        else if (S1 >= rem) { b = 1; sn = S1 - vv1; }
        else if (S0 >= rem) { b = 0; sn = S0 - vv0; }
        uint32_t packed = (b >= 0) ? (((uint32_t)b << 16) | sn) : 0u;
        // suffix counts are monotone-decreasing in digit index, so lanes with
        // a qualifying digit form a prefix [0..L]; the crossing digit lives in
        // the HIGHEST such lane: 1 ballot + 1 broadcast shfl replaces the
        // 6-step shfl_xor max-reduce.
        unsigned long long qm = __ballot(b >= 0);
        if (qm != 0ull) {
            int selLane = 63 - __builtin_clzll(qm);
            uint32_t pk = (uint32_t)__shfl((int)packed, selLane, 64);
            dsel = (uint32_t)(4 * selLane) + (pk >> 16);
            rem -= (pk & 0xFFFFu);
            sel = 1u;
        } else {
            dsel = 0u;
            sel = 0u;
        }
    }

    float thr = 0.0f;
    bool need_fallback = (sel == 0u) || (dsel == 255u);

    if (!need_fallback) {
        const uint32_t hi16 = 0x3F80u + dsel;
        // scatter survivors (order irrelevant); may include a few elements in
        // [1.09375, T0) when dsel==0x0C — all strictly below every histogrammed
        // member, and rem <= member count, so the rem-th largest is unaffected.
        #pragma unroll
        for (int e = 0; e < 16; ++e) {
            uint32_t ub = __float_as_uint(xb[e]);
            if ((ub >> 16) == hi16) {
                uint32_t pos = atomicAdd(&s_m2, 1u);
                if (pos < SURV_CAP) s_cand[pos] = ub;
            }
        }
        __syncthreads();
        const uint32_t m2 = s_m2;        // block-uniform broadcast read
        if (m2 <= SURV_CAP) {
            // replicated 16-bit ballot descent: every wave loads the same
            // survivors, so every wave's ballot counts are the global counts.
            uint32_t cv = ((uint32_t)lane < m2) ? s_cand[lane] : ((~hi16) << 16);
            uint32_t cur = 0;
            #pragma unroll
            for (int bpos = 15; bpos >= 0; --bpos) {
                uint32_t t  = (hi16 << 16) | cur | (1u << bpos);
                uint32_t mk = ~((1u << bpos) - 1u);
                uint32_t c  = (uint32_t)__popcll(__ballot(((cv ^ t) & mk) == 0u));
                if (c >= rem) cur |= (1u << bpos);
                else          rem -= c;
            }
            thr = __uint_as_float((hi16 << 16) | cur);
        } else {
            need_fallback = true;
        }
    }

    if (need_fallback) {
        // exact 4-pass orderable radix over all 4096 elements (any input)
        __syncthreads();
        {
            uint4* h4 = (uint4*)s_hist;
            uint4 z; z.x = z.y = z.z = z.w = 0u;
            #pragma unroll
            for (int j = 0; j < 3; ++j) {
                int idx = tid + j * TPB;
                if (idx < NHWORDS / 4) h4[idx] = z;
            }
        }
        __syncthreads();
        uint32_t prefix = 0;
        rem = k;
        const uint32_t pmasks[4] = {0u, 0xFF000000u, 0xFFFF0000u, 0xFFFFFF00u};
        #pragma unroll 1
        for (int pass = 0; pass < 4; ++pass) {
            const int shift = 24 - pass * 8;
            const uint32_t pm = pmasks[pass];
            #pragma unroll
            for (int e = 0; e < 16; ++e) {
                uint32_t ou = orderable(__float_as_uint(xb[e]));
                if (((ou ^ prefix) & pm) == 0u)
                    atomicAdd(&hc[(ou >> shift) & 255u], 1u);
            }
            __syncthreads();
            // reduce copies of bin `tid` (consecutive-bin reads: conflict-free),
            // zero them for the next pass
            {
                uint32_t sum = 0;
                #pragma unroll
                for (int c = 0; c < NCOPY; ++c) {
                    sum += s_hist[c * CSTR + tid];
                    s_hist[c * CSTR + tid] = 0u;
                }
                s_cnt[tid] = sum;
            }
            __syncthreads();
            // replicated suffix-scan + ballot digit pick over s_cnt
            uint4 v = ((const uint4*)s_cnt)[lane];
            uint32_t s3 = v.w, s2 = v.z + s3, s1 = v.y + s2, s0 = v.x + s1;
            uint32_t T = s0;
            #pragma unroll
            for (int off = 1; off < 64; off <<= 1) {
                uint32_t t = (uint32_t)__shfl_down((int)T, off, 64);
                if (lane + off < 64) T += t;
            }
            uint32_t Tex = T - s0;
            uint32_t S0 = Tex + s0, S1 = Tex + s1, S2 = Tex + s2, S3 = Tex + s3;
            int b = -1; uint32_t sn = 0;
            if (S3 >= rem)      { b = 3; sn = S3 - v.w; }
            else if (S2 >= rem) { b = 2; sn = S2 - v.z; }
            else if (S1 >= rem) { b = 1; sn = S1 - v.y; }
            else if (S0 >= rem) { b = 0; sn = S0 - v.x; }
            uint32_t packed = (b >= 0) ? (((uint32_t)b << 16) | sn) : 0u;
            unsigned long long qm = __ballot(b >= 0);
            int selLane = 63 - __builtin_clzll(qm | 1ull);   // qm!=0 guaranteed here
            uint32_t pk = (uint32_t)__shfl((int)packed, selLane, 64);
            prefix |= ((uint32_t)(4 * selLane) + (pk >> 16)) << shift;
            rem -= (pk & 0xFFFFu);
        }
        // orderable-space -> float bits
        uint32_t tu = (prefix & 0x80000000u) ? (prefix & 0x7FFFFFFFu) : ~prefix;
        thr = __uint_as_float(tu);
    }

    // epilogue: mask from boosted (regs) vs thr, values from x (regs)
    #pragma unroll
    for (int j = 0; j < 4; ++j) {
        float4 o;
        o.x = (xb[j * 4 + 0] >= thr) ? xv[j].x : 0.0f;
        o.y = (xb[j * 4 + 1] >= thr) ? xv[j].y : 0.0f;
        o.z = (xb[j * 4 + 2] >= thr) ? xv[j].z : 0.0f;
        o.w = (xb[j * 4 + 3] >= thr) ? xv[j].w : 0.0f;
        orow[tid + j * TPB] = o;
    }
}

extern "C" void kernel_launch(void* const* d_in, const int* in_sizes, int n_in,
                              void* d_out, int out_size, void* d_ws, size_t ws_size,
                              hipStream_t stream) {
    const float* x  = (const float*)d_in[0];
    const float* dc = (const float*)d_in[1];
    const int*   kp = (const int*)d_in[2];
    float* out = (float*)d_out;
    float* bf  = (float*)d_ws;                 // 4096 floats of scratch

    const int n    = in_sizes[1];              // 4096
    const int rows = in_sizes[0] / n;          // 8192

    boost_kernel<<<(n + TPB - 1) / TPB, TPB, 0, stream>>>(dc, kp, bf);
    kwinner_kernel<<<rows, TPB, 0, stream>>>(x, bf, kp, out);
}